// Round 7
// baseline (446.186 us; speedup 1.0000x reference)
//
#include <hip/hip_runtime.h>

// MRMSNorm: x (4,4096,4096) fp32, scale (4096,) fp32.
// Per row: 5 nested RMS norms at prefix sizes {256,512,1024,2048,4096}.
// out[d] = x[d] * rsqrt(sumsq(x[0:s])/s + 1e-6) * scale[d], s = segment of d.
//
// STRUCTURE: one WAVE per row (not one block). 64 lanes x 16 float4
// = full 4096-float row in registers. No LDS, no __syncthreads, no cross-wave
// coupling -> every wave is an independent stream (copy-like latency hiding).
// Segment sums via 5-chain x 6-level __shfl_xor butterfly (all lanes end up
// with the sums; no broadcast step).
//
// Chunk c (c=0..15) = float cols [256c, 256c+256); lane l owns float4 at
// f32x4-index c*64+l. Segment boundaries align with chunks:
//   seg0=c0, seg1=c1, seg2=c2-3, seg3=c4-7, seg4=c8-15  -> per-chunk uniform
//   rrms, zero divergence.

#define D 4096

typedef float f32x4 __attribute__((ext_vector_type(4)));

__global__ __launch_bounds__(256) void mrms_kernel(
    const float* __restrict__ x,
    const float* __restrict__ scale,
    float* __restrict__ out)
{
    const int lane = threadIdx.x & 63;
    const int row  = blockIdx.x * 4 + (threadIdx.x >> 6);
    const size_t base = (size_t)row * D;
    const f32x4* __restrict__ xr   = reinterpret_cast<const f32x4*>(x + base);
    f32x4* __restrict__ outr       = reinterpret_cast<f32x4*>(out + base);
    const f32x4* __restrict__ sc4  = reinterpret_cast<const f32x4*>(scale);

    // Whole row into registers (16 coalesced dwordx4 per lane), plus scale
    // (16 KB, same for all rows -> L1-resident after first touch).
    f32x4 v[16];
    #pragma unroll
    for (int c = 0; c < 16; ++c) v[c] = xr[c * 64 + lane];
    f32x4 g[16];
    #pragma unroll
    for (int c = 0; c < 16; ++c) g[c] = sc4[c * 64 + lane];

    float ss[16];
    #pragma unroll
    for (int c = 0; c < 16; ++c)
        ss[c] = v[c].x*v[c].x + v[c].y*v[c].y + v[c].z*v[c].z + v[c].w*v[c].w;

    // Per-lane partial per segment.
    float a0 = ss[0];
    float a1 = ss[1];
    float a2 = ss[2] + ss[3];
    float a3 = (ss[4] + ss[5]) + (ss[6] + ss[7]);
    float a4 = ((ss[8] + ss[9]) + (ss[10] + ss[11]))
             + ((ss[12] + ss[13]) + (ss[14] + ss[15]));

    // 64-lane butterfly: 5 independent chains (ILP), 6 dependent levels each.
    #pragma unroll
    for (int off = 1; off < 64; off <<= 1) {
        a0 += __shfl_xor(a0, off, 64);
        a1 += __shfl_xor(a1, off, 64);
        a2 += __shfl_xor(a2, off, 64);
        a3 += __shfl_xor(a3, off, 64);
        a4 += __shfl_xor(a4, off, 64);
    }

    const float cum0 = a0;
    const float cum1 = cum0 + a1;
    const float cum2 = cum1 + a2;
    const float cum3 = cum2 + a3;
    const float cum4 = cum3 + a4;

    const float EPS = 1e-6f;
    const float r0 = rsqrtf(cum0 * (1.0f / 256.0f)  + EPS);
    const float r1 = rsqrtf(cum1 * (1.0f / 512.0f)  + EPS);
    const float r2 = rsqrtf(cum2 * (1.0f / 1024.0f) + EPS);
    const float r3 = rsqrtf(cum3 * (1.0f / 2048.0f) + EPS);
    const float r4 = rsqrtf(cum4 * (1.0f / 4096.0f) + EPS);

    // Statically-indexed rrms table (fully unrolled -> stays in registers).
    const float rr[16] = { r0, r1, r2, r2,
                           r3, r3, r3, r3,
                           r4, r4, r4, r4, r4, r4, r4, r4 };

    #pragma unroll
    for (int c = 0; c < 16; ++c) {
        f32x4 o;
        o.x = v[c].x * rr[c] * g[c].x;
        o.y = v[c].y * rr[c] * g[c].y;
        o.z = v[c].z * rr[c] * g[c].z;
        o.w = v[c].w * rr[c] * g[c].w;
        __builtin_nontemporal_store(o, &outr[c * 64 + lane]);
    }
}

extern "C" void kernel_launch(void* const* d_in, const int* in_sizes, int n_in,
                              void* d_out, int out_size, void* d_ws, size_t ws_size,
                              hipStream_t stream) {
    const float* x     = (const float*)d_in[0];
    const float* scale = (const float*)d_in[1];
    float* out         = (float*)d_out;

    const int nrows = in_sizes[0] / D;       // 16384
    mrms_kernel<<<nrows / 4, 256, 0, stream>>>(x, scale, out);
}